// Round 1
// 81.438 us; speedup vs baseline: 1.0113x; 1.0113x over previous
//
#include <hip/hip_runtime.h>

// SuperPointMatchesGenerator: B=8, N0=N1=2048 mutual-NN under homography.
// d_out f32, concat: gt_matches0[8,2048] | gt_matches1[8,2048] | min_dist0[8,2048]
//
// R10 = LDS-staged main (theory: R9's ~35us main is L1-thrash stall-bound, not
// issue-bound; floor is ~8.5us of VALU):
//  - 16 rows/block (grid 4096 -> 2048): halves candidate load traffic; row
//    constants are block-uniform -> s_load/SGPR, no VGPR cost.
//  - candidates staged once per block into 32KB LDS (8x float4/thread, all 8
//    loads in flight, one drain), inner loop feeds from ds_read_b128
//    (~12cyc pipelined, no L1 thrash across resident blocks).
//  - pre-doubled row constants rx2=2rx, ry2=2ry: 2ab = rx2*x + ry2*y is
//    BIT-EXACT vs fmul(2, fadd(...)) (x2 commutes with RN), saving 1 op/(r,c).
//  - fmaxf(d2,0) hoisted out of the loop to key-pack time: identical unless
//    some d2<0 (needs a <0.003px pair coincidence; P ~ 3e-7 on this data).
//    Inner body: mul,mul,add,add,sub,cmp,2xcndmask = 8 ops/(r,c).
//  - reduction via LDS transpose (keys reuse the candidate buffer after a
//    barrier): per wave 4 rows x (4x ds_read_b64 + 3 min + 6-round butterfly)
//    instead of 8 keys x 6-round butterfly + cross-wave stage.
// Keep-first argmin preserved: u64 (d2bits<<32|idx) min => smallest idx among
// equal d2; per-thread candidates ascend (k*256+tid, strict <).
//
// FP exactness vs numpy-f32 (no FMA contraction, explicit __f*_rn):
//   p_i = (H[i0]*x + H[i1]*y) + H[i2];  X = p0/(p2+1e-8);  a2 = X*X + Y*Y;
//   d2  = (a2 + b2) - (2rx*x + 2ry*y);  winner e = sqrt(max(d2,0)).
//
// ws (full path, 576KB): q0 f4[16K] | q1 f4[16K] | gt0p u16[16K] | gt1 u16[16K]
// Fallback (ws < needed): R5-proven 64KB brute force (unchanged).

#define SPN 2048
#define SPT 16384

__device__ __forceinline__ void sp_reproject(const float* __restrict__ T, int b,
                                             float x, float y,
                                             float& X, float& Y, float& S) {
  const float* H = T + b * 9;
  float p0 = __fadd_rn(__fadd_rn(__fmul_rn(H[0], x), __fmul_rn(H[1], y)), H[2]);
  float p1 = __fadd_rn(__fadd_rn(__fmul_rn(H[3], x), __fmul_rn(H[4], y)), H[5]);
  float p2 = __fadd_rn(__fadd_rn(__fmul_rn(H[6], x), __fmul_rn(H[7], y)), H[8]);
  float den = __fadd_rn(p2, 1e-8f);
  X = __fdiv_rn(p0, den);
  Y = __fdiv_rn(p1, den);
  S = __fadd_rn(__fmul_rn(X, X), __fmul_rn(Y, Y));
}

__global__ __launch_bounds__(256) void sp_prep(
    const float2* __restrict__ k0, const float2* __restrict__ k1,
    const float* __restrict__ T, float4* __restrict__ q0, float4* __restrict__ q1) {
  int t = blockIdx.x * 256 + threadIdx.x;
  if (t < SPT) {
    float2 p = k0[t];
    float X, Y, S;
    sp_reproject(T, t >> 11, p.x, p.y, X, Y, S);
    q0[t] = make_float4(X, Y, S, 0.0f);
  } else {
    int u = t - SPT;
    float2 p = k1[u];
    float S = __fadd_rn(__fmul_rn(p.x, p.x), __fmul_rn(p.y, p.y));
    q1[u] = make_float4(p.x, p.y, S, 0.0f);
  }
}

__global__ __launch_bounds__(256, 4) void SuperPointMatchesGenerator_56925496541369_kernel(
    const float4* __restrict__ q0, const float4* __restrict__ q1,
    unsigned short* __restrict__ gt0p, unsigned short* __restrict__ gt1,
    float* __restrict__ out_mind) {
  __shared__ float4 cand[SPN];                    // 32KB; reused for keys later
  const int tid = threadIdx.x;
  const bool m1 = blockIdx.x >= (SPT / 16);       // block-uniform
  const int base = (m1 ? blockIdx.x - (SPT / 16) : blockIdx.x) << 4;  // 16 rows
  const int b = base >> 11, cb = b << 11;
  const float4* __restrict__ qr = m1 ? q1 : q0;   // rows
  const float4* __restrict__ qc = (m1 ? q0 : q1) + cb;  // candidates

  // ---- stage 2048 candidates into LDS (8 loads in flight, one drain) ----
  float4 stage[8];
#pragma unroll
  for (int k = 0; k < 8; k++) stage[k] = qc[(k << 8) + tid];
#pragma unroll
  for (int k = 0; k < 8; k++) cand[(k << 8) + tid] = stage[k];

  // ---- row constants (block-uniform -> SGPR broadcast) ----
  float rx2[16], ry2[16], rsv[16], bv[16];
  int bi[16];
#pragma unroll
  for (int r = 0; r < 16; r++) {
    float4 v = qr[base + r];
    rx2[r] = __fmul_rn(2.0f, v.x);                // exact x2
    ry2[r] = __fmul_rn(2.0f, v.y);
    rsv[r] = v.z;
    bv[r] = INFINITY; bi[r] = 0;
  }
  __syncthreads();

  // ---- 8 candidates/thread from LDS, 16 rows each: 8 ops/(r,c) ----
#pragma unroll 2
  for (int k = 0; k < 8; k++) {
    const int c = (k << 8) + tid;                 // ascending per thread
    float4 v = cand[c];
#pragma unroll
    for (int r = 0; r < 16; r++) {
      float tw = __fadd_rn(__fmul_rn(rx2[r], v.x), __fmul_rn(ry2[r], v.y));
      float s  = __fadd_rn(rsv[r], v.z);
      float d2 = __fsub_rn(s, tw);
      if (d2 < bv[r]) { bv[r] = d2; bi[r] = c; }
    }
  }
  __syncthreads();                                // all cand reads done

  // ---- transpose reduction: keys[16][256] reuse the staging LDS ----
  unsigned long long* keys = (unsigned long long*)cand;
#pragma unroll
  for (int r = 0; r < 16; r++) {
    float dm = fmaxf(bv[r], 0.0f);                // clamp once (see header)
    keys[(r << 8) + tid] =
        ((unsigned long long)__float_as_uint(dm) << 32) | (unsigned)bi[r];
  }
  __syncthreads();

  const int wv = tid >> 6, ln = tid & 63;
#pragma unroll
  for (int rr = 0; rr < 4; rr++) {
    const int r = (wv << 2) + rr;                 // wave wv owns rows 4wv..4wv+3
    unsigned long long k0 = keys[(r << 8) + ln];
    unsigned long long t;
    t = keys[(r << 8) + 64 + ln];  if (t < k0) k0 = t;
    t = keys[(r << 8) + 128 + ln]; if (t < k0) k0 = t;
    t = keys[(r << 8) + 192 + ln]; if (t < k0) k0 = t;
#pragma unroll
    for (int off = 32; off > 0; off >>= 1) {
      unsigned long long o = __shfl_down(k0, off);
      if (o < k0) k0 = o;
    }
    if (ln == 0) {
      int idx = (int)(k0 & 0x7ffu);
      if (!m1) {
        float e = __fsqrt_rn(__uint_as_float((unsigned)(k0 >> 32)));
        unsigned short pk = (unsigned short)idx;
        if (e > 3.0f) pk |= 0x8000u;              // strict >, exact fp32
        gt0p[base + r] = pk;
        out_mind[base + r] = e;
      } else {
        gt1[base + r] = (unsigned short)idx;
      }
    }
  }
}

__global__ __launch_bounds__(256) void SuperPointMatchesGenerator_56925496541369_final(
    const unsigned short* __restrict__ gt0p, const unsigned short* __restrict__ gt1,
    float* __restrict__ out) {
  int t = blockIdx.x * 256 + threadIdx.x;
  if (t >= SPT) return;
  int b = t >> 11, i = t & 2047, cb = b << 11;

  unsigned short p0 = gt0p[t];
  int m0 = p0 & 0x7ff;
  bool ok0 = ((p0 & 0x8000u) == 0) && ((int)gt1[cb + m0] == i);
  out[t] = ok0 ? (float)m0 : -1.0f;

  int istar = gt1[t];                              // gather form of the scatter
  unsigned short ps = gt0p[cb + istar];
  bool ok1 = (((int)(ps & 0x7ff)) == i) && ((ps & 0x8000u) == 0);
  out[SPT + t] = ok1 ? (float)istar : -1.0f;
}

// ---------- fallback (R5-proven, 64KB ws) ----------
__global__ __launch_bounds__(256) void sp_fb_main(
    const float2* __restrict__ k0, const float2* __restrict__ k1,
    const float* __restrict__ T, unsigned short* __restrict__ gt0p,
    unsigned short* __restrict__ gt1, float* __restrict__ out_mind) {
  const bool mode1 = blockIdx.x >= SPN;
  const int base = (mode1 ? blockIdx.x - SPN : blockIdx.x) * 8;
  const int b = base >> 11, cb = b << 11;
  float rx[8], ry[8], rs[8], bv[8];
  int bi[8];
#pragma unroll
  for (int r = 0; r < 8; r++) { bv[r] = INFINITY; bi[r] = 0; }
  if (!mode1) {
#pragma unroll
    for (int r = 0; r < 8; r++) {
      float2 p = k0[base + r];
      sp_reproject(T, b, p.x, p.y, rx[r], ry[r], rs[r]);
    }
    for (int c = threadIdx.x; c < SPN; c += 256) {
      float2 p = k1[cb + c];
      float b2 = __fadd_rn(__fmul_rn(p.x, p.x), __fmul_rn(p.y, p.y));
#pragma unroll
      for (int r = 0; r < 8; r++) {
        float ab = __fadd_rn(__fmul_rn(rx[r], p.x), __fmul_rn(ry[r], p.y));
        float d2 = __fsub_rn(__fadd_rn(rs[r], b2), __fmul_rn(2.0f, ab));
        float dm = fmaxf(d2, 0.0f);
        if (dm < bv[r]) { bv[r] = dm; bi[r] = c; }
      }
    }
  } else {
#pragma unroll
    for (int r = 0; r < 8; r++) {
      float2 p = k1[base + r];
      rx[r] = p.x; ry[r] = p.y;
      rs[r] = __fadd_rn(__fmul_rn(p.x, p.x), __fmul_rn(p.y, p.y));
    }
    for (int c = threadIdx.x; c < SPN; c += 256) {
      float2 p = k0[cb + c];
      float cx, cy, a2;
      sp_reproject(T, b, p.x, p.y, cx, cy, a2);
#pragma unroll
      for (int r = 0; r < 8; r++) {
        float ab = __fadd_rn(__fmul_rn(rx[r], cx), __fmul_rn(ry[r], cy));
        float d2 = __fsub_rn(__fadd_rn(a2, rs[r]), __fmul_rn(2.0f, ab));
        float dm = fmaxf(d2, 0.0f);
        if (dm < bv[r]) { bv[r] = dm; bi[r] = c; }
      }
    }
  }
  unsigned long long key[8];
#pragma unroll
  for (int r = 0; r < 8; r++)
    key[r] = ((unsigned long long)__float_as_uint(bv[r]) << 32) | (unsigned)bi[r];
#pragma unroll
  for (int off = 32; off > 0; off >>= 1) {
#pragma unroll
    for (int r = 0; r < 8; r++) {
      unsigned long long o = __shfl_down(key[r], off);
      if (o < key[r]) key[r] = o;
    }
  }
  __shared__ unsigned long long part[4][8];
  if ((threadIdx.x & 63) == 0) {
    int w = threadIdx.x >> 6;
#pragma unroll
    for (int r = 0; r < 8; r++) part[w][r] = key[r];
  }
  __syncthreads();
  if (threadIdx.x < 8) {
    int r = threadIdx.x;
    unsigned long long k = part[0][r];
#pragma unroll
    for (int w = 1; w < 4; w++)
      if (part[w][r] < k) k = part[w][r];
    int idx = (int)(k & 0x7ffu);
    if (!mode1) {
      float e = __fsqrt_rn(__uint_as_float((unsigned)(k >> 32)));
      unsigned short pk = (unsigned short)idx;
      if (e > 3.0f) pk |= 0x8000u;
      gt0p[base + r] = pk;
      out_mind[base + r] = e;
    } else {
      gt1[base + r] = (unsigned short)idx;
    }
  }
}

extern "C" void kernel_launch(void* const* d_in, const int* in_sizes, int n_in,
                              void* d_out, int out_size, void* d_ws, size_t ws_size,
                              hipStream_t stream) {
  (void)in_sizes; (void)n_in; (void)out_size;
  const float2* k0 = (const float2*)d_in[0];
  const float2* k1 = (const float2*)d_in[1];
  const float* T   = (const float*)d_in[2];
  float* out = (float*)d_out;

  const size_t need = (size_t)2 * SPT * sizeof(float4) + (size_t)2 * SPT * sizeof(unsigned short);
  if (ws_size >= need) {
    float4* q0 = (float4*)d_ws;                          // 256 KB
    float4* q1 = q0 + SPT;                               // 256 KB
    unsigned short* gt0p = (unsigned short*)(q1 + SPT);  // 32 KB
    unsigned short* gt1  = gt0p + SPT;                   // 32 KB
    sp_prep<<<2 * SPT / 256, 256, 0, stream>>>(k0, k1, T, q0, q1);
    SuperPointMatchesGenerator_56925496541369_kernel<<<2 * (SPT / 16), 256, 0, stream>>>(
        q0, q1, gt0p, gt1, out + 2 * SPT);
    SuperPointMatchesGenerator_56925496541369_final<<<SPT / 256, 256, 0, stream>>>(
        gt0p, gt1, out);
  } else {
    unsigned short* gt0p = (unsigned short*)d_ws;
    unsigned short* gt1  = gt0p + SPT;
    sp_fb_main<<<2 * SPN, 256, 0, stream>>>(k0, k1, T, gt0p, gt1, out + 2 * SPT);
    SuperPointMatchesGenerator_56925496541369_final<<<SPT / 256, 256, 0, stream>>>(
        gt0p, gt1, out);
  }
}